// Round 6
// baseline (1755.142 us; speedup 1.0000x reference)
//
#include <hip/hip_runtime.h>
#include <math.h>

#define NBASES 16
#define HID 64
#define FIL 64
#define TBL 8192
#define DMAX 8.0f
#define TSCALE (8191.0f / 8.0f)

// ShiftedSoftplus: softplus(x) - log(2), overflow-safe form.
__device__ __forceinline__ float sspf(float x) {
    return fmaxf(x, 0.f) + __logf(1.f + __expf(-fabsf(x))) - 0.69314718056f;
}

// ---------------- CSR build: histogram of dst ----------------
__global__ void k_count(const int* __restrict__ ei, int E, int* __restrict__ cnt) {
    int e = blockIdx.x * blockDim.x + threadIdx.x;
    if (e >= E) return;
    atomicAdd(&cnt[ei[E + e]], 1);
}

// ---- 3-phase scan: per-block exclusive scan + carry, carry scan, add ----
__global__ void k_scan_blk(const int* __restrict__ cnt, int N,
                           int* __restrict__ row_start, int* __restrict__ carry) {
    __shared__ int s[1024];
    int tid = threadIdx.x;
    int idx = blockIdx.x * 1024 + tid;
    int v = (idx < N) ? cnt[idx] : 0;
    s[tid] = v;
    __syncthreads();
    for (int off = 1; off < 1024; off <<= 1) {
        int t = (tid >= off) ? s[tid - off] : 0;
        __syncthreads();
        s[tid] += t;
        __syncthreads();
    }
    if (idx < N) row_start[idx] = s[tid] - v;     // within-block exclusive
    if (tid == 1023) carry[blockIdx.x] = s[1023]; // block total
}

__global__ void k_scan_carry(const int* __restrict__ carry, int nblk,
                             int* __restrict__ carry_ex) {
    __shared__ int s[1024];
    int tid = threadIdx.x;
    int v = (tid < nblk) ? carry[tid] : 0;
    s[tid] = v;
    __syncthreads();
    for (int off = 1; off < 1024; off <<= 1) {
        int t = (tid >= off) ? s[tid - off] : 0;
        __syncthreads();
        s[tid] += t;
        __syncthreads();
    }
    if (tid < nblk) carry_ex[tid] = s[tid] - v;
}

__global__ void k_scan_add(int* __restrict__ row_start, const int* __restrict__ carry_ex,
                           int N, int E, int* __restrict__ cursor) {
    int i = blockIdx.x * blockDim.x + threadIdx.x;
    if (i >= N) return;
    int r = row_start[i] + carry_ex[i >> 10];
    row_start[i] = r;
    cursor[i] = r;
    if (i == 0) row_start[N] = E;
}

// fill sorted-edge records: {src, dst, d, C} packed in one float4
__global__ void k_fill(const float* __restrict__ pos, const float* __restrict__ shifts,
                       const int* __restrict__ ei, int E, int* __restrict__ cursor,
                       float4* __restrict__ e_pack) {
    int e = blockIdx.x * blockDim.x + threadIdx.x;
    if (e >= E) return;
    int s = ei[e], t = ei[E + e];
    float dx = pos[t * 3 + 0] - pos[s * 3 + 0] + shifts[e * 3 + 0];
    float dy = pos[t * 3 + 1] - pos[s * 3 + 1] + shifts[e * 3 + 1];
    float dz = pos[t * 3 + 2] - pos[s * 3 + 2] + shifts[e * 3 + 2];
    float d = sqrtf(dx * dx + dy * dy + dz * dz);
    float C = 0.5f * (cosf(d * 0.6283185307179586f) + 1.0f); // pi/CUTOFF = pi/5
    int p = atomicAdd(&cursor[t], 1);
    float4 rec;
    rec.x = __int_as_float(s);
    rec.y = __int_as_float(t);
    rec.z = d;
    rec.w = C;
    e_pack[p] = rec;
}

// ---------------- W(d) lookup tables (fp16): thread = (entry, 4-filter chunk) ----------------
__global__ void __launch_bounds__(256) k_table(
    const float* __restrict__ w1, const float* __restrict__ b1,
    const float* __restrict__ w2, const float* __restrict__ b2,
    _Float16* __restrict__ tab) {
    int i = blockIdx.x * blockDim.x + threadIdx.x; // ((l*TBL + ti)<<4) | chunk
    if (i >= 2 * TBL * 16) return;
    int chunk = i & 15;
    int ent = i >> 4;
    int l = ent >> 13;
    int ti = ent & (TBL - 1);
    int f0 = chunk * 4;
    const float* w1l = w1 + l * (FIL * NBASES);
    const float* b1l = b1 + l * FIL;
    const float* w2l = w2 + l * (FIL * FIL);
    const float* b2l = b2 + l * FIL;
    float d = (float)ti * (DMAX / (float)(TBL - 1));
    float g[16];
#pragma unroll
    for (int b = 0; b < NBASES; b++) {
        float u = d - (float)b * (5.0f / 15.0f);
        g[b] = __expf(-4.5f * u * u);
    }
    float a0 = b2l[f0 + 0], a1 = b2l[f0 + 1], a2 = b2l[f0 + 2], a3 = b2l[f0 + 3];
#pragma unroll 4
    for (int j = 0; j < FIL; j++) {
        float tt = b1l[j];
#pragma unroll
        for (int b = 0; b < NBASES; b++) tt += w1l[j * NBASES + b] * g[b];
        float hj = sspf(tt);
        a0 += w2l[(f0 + 0) * FIL + j] * hj;
        a1 += w2l[(f0 + 1) * FIL + j] * hj;
        a2 += w2l[(f0 + 2) * FIL + j] * hj;
        a3 += w2l[(f0 + 3) * FIL + j] * hj;
    }
    _Float16* o = tab + (size_t)ent * FIL + f0;
    o[0] = (_Float16)a0; o[1] = (_Float16)a1; o[2] = (_Float16)a2; o[3] = (_Float16)a3;
}

// helper: LDS-broadcast matvec, lane = output index. v staged in buf (64 floats, wave-private).
__device__ __forceinline__ float matvec64(const float* __restrict__ wrow, const float* __restrict__ buf) {
    const float4* w4 = (const float4*)wrow;
    const float4* b4 = (const float4*)buf;
    float acc = 0.f;
#pragma unroll
    for (int jc = 0; jc < 16; jc++) {
        float4 ww = w4[jc];   // per-lane row, L1-resident (16KB working set)
        float4 vv = b4[jc];   // uniform LDS address -> broadcast, conflict-free
        acc += ww.x * vv.x + ww.y * vv.y + ww.z * vv.z + ww.w * vv.w;
    }
    return acc;
}

// ---------------- fused embed + layer0 lin1 (wave per node, lane = feature) ----------------
__global__ void __launch_bounds__(256) k_embed_lin1(
    const float* __restrict__ attrs, const float* __restrict__ wv,
    const float* __restrict__ w, int N,
    float* __restrict__ h, _Float16* __restrict__ xfh) {
    __shared__ float buf[4][64];
    int n = (blockIdx.x * blockDim.x + threadIdx.x) >> 6;
    int lane = threadIdx.x & 63;
    int ws = threadIdx.x >> 6;
    if (n >= N) return;
    float a0 = attrs[n * 5 + 0], a1 = attrs[n * 5 + 1], a2 = attrs[n * 5 + 2],
          a3 = attrs[n * 5 + 3], a4 = attrs[n * 5 + 4];       // uniform -> broadcast
    const float* wr = wv + lane * 5;
    float hv = a0 * wr[0] + a1 * wr[1] + a2 * wr[2] + a3 * wr[3] + a4 * wr[4];
    h[(size_t)n * HID + lane] = hv;
    buf[ws][lane] = hv;                                        // wave-lockstep staging
    float xv = matvec64(w + lane * 64, buf[ws]);
    xfh[(size_t)n * FIL + lane] = (_Float16)xv;
}

// ---------------- edge aggregate: wave per node, fp16 gathers, 2x unrolled ----------------
__global__ void __launch_bounds__(256, 8) k_edge_agg(
    const float4* __restrict__ e_pack, const int* __restrict__ row_start, int N,
    const _Float16* __restrict__ tab, const _Float16* __restrict__ xf,
    float* __restrict__ agg) {
    int n = (blockIdx.x * blockDim.x + threadIdx.x) >> 6;
    int lane = threadIdx.x & 63;
    if (n >= N) return;
    int rs = row_start[n], re = row_start[n + 1];
    float acc = 0.f;
    int r = rs;
#define EDGE_TERM(ep) do { \
        int s_ = __float_as_int((ep).x); \
        float x_ = (ep).z * TSCALE; \
        int i0_ = (int)x_; if (i0_ > TBL - 2) i0_ = TBL - 2; \
        float fr_ = fminf(x_ - (float)i0_, 1.0f); \
        float t0_ = (float)tab[(size_t)i0_ * FIL + lane]; \
        float t1_ = (float)tab[(size_t)(i0_ + 1) * FIL + lane]; \
        float xv_ = (float)xf[(size_t)s_ * FIL + lane]; \
        acc += xv_ * (t0_ + (t1_ - t0_) * fr_) * (ep).w; \
    } while (0)
    for (; r + 2 <= re; r += 2) {
        float4 e0 = e_pack[r];
        float4 e1 = e_pack[r + 1];
        EDGE_TERM(e0);
        EDGE_TERM(e1);
    }
    if (r < re) {
        float4 e0 = e_pack[r];
        EDGE_TERM(e0);
    }
    agg[(size_t)n * FIL + lane] = acc;
#undef EDGE_TERM
}

// ---------------- fused layer-0 node update: h += lin(ssp(lin2(agg))); xf_next = h@lin1_1^T ----------------
__global__ void __launch_bounds__(256) k_node_l0(
    const float* __restrict__ agg,
    const float* __restrict__ lin2w, const float* __restrict__ lin2b,
    const float* __restrict__ linw, const float* __restrict__ linb,
    const float* __restrict__ lin1w_next, int N,
    float* __restrict__ h, _Float16* __restrict__ xfh) {
    __shared__ float buf[4][64];
    int n = (blockIdx.x * blockDim.x + threadIdx.x) >> 6;
    int lane = threadIdx.x & 63;
    int ws = threadIdx.x >> 6;
    if (n >= N) return;
    buf[ws][lane] = agg[(size_t)n * FIL + lane];
    float tmpv = sspf(lin2b[lane] + matvec64(lin2w + lane * 64, buf[ws]));
    buf[ws][lane] = tmpv;                                      // wave-lockstep: prior reads done
    float hnew = h[(size_t)n * HID + lane] + linb[lane] + matvec64(linw + lane * 64, buf[ws]);
    h[(size_t)n * HID + lane] = hnew;
    buf[ws][lane] = hnew;
    float xv = matvec64(lin1w_next + lane * 64, buf[ws]);
    xfh[(size_t)n * FIL + lane] = (_Float16)xv;
}

// ---------------- fused layer-1 node update + readout MLP + scatter-mean ----------------
__global__ void __launch_bounds__(256) k_node_l1(
    const float* __restrict__ agg,
    const float* __restrict__ lin2w, const float* __restrict__ lin2b,
    const float* __restrict__ linw, const float* __restrict__ linb,
    const float* __restrict__ h, const int* __restrict__ batch,
    const float* __restrict__ ow1, const float* __restrict__ ob1,
    const float* __restrict__ ow2, const float* __restrict__ ob2, int N,
    float* __restrict__ sums, float* __restrict__ counts) {
    __shared__ float buf[4][64];
    int n = (blockIdx.x * blockDim.x + threadIdx.x) >> 6;
    int lane = threadIdx.x & 63;
    int ws = threadIdx.x >> 6;
    if (n >= N) return;
    buf[ws][lane] = agg[(size_t)n * FIL + lane];
    float tmpv = sspf(lin2b[lane] + matvec64(lin2w + lane * 64, buf[ws]));
    buf[ws][lane] = tmpv;
    float hnew = h[(size_t)n * HID + lane] + linb[lane] + matvec64(linw + lane * 64, buf[ws]);
    buf[ws][lane] = hnew;                                      // h never written: consumed here
    float r = 0.f;
    if (lane < 32) {
        float racc = ob1[lane] + matvec64(ow1 + lane * 64, buf[ws]);
        r = sspf(racc) * ow2[lane];
    }
#pragma unroll
    for (int m = 1; m < 64; m <<= 1) r += __shfl_xor(r, m, 64);
    if (lane == 0) {
        int b = batch[n];
        unsafeAtomicAdd(&sums[b], r + ob2[0]);
        unsafeAtomicAdd(&counts[b], 1.0f);
    }
}

__global__ void k_finalize(const float* __restrict__ sums, const float* __restrict__ counts,
                           int G, float* __restrict__ out) {
    int g = blockIdx.x * blockDim.x + threadIdx.x;
    if (g >= G) return;
    out[g] = sums[g] / fmaxf(counts[g], 1.0f);
}

extern "C" void kernel_launch(void* const* d_in, const int* in_sizes, int n_in,
                              void* d_out, int out_size, void* d_ws, size_t ws_size,
                              hipStream_t stream) {
    const float* pos    = (const float*)d_in[0];
    const float* shifts = (const float*)d_in[1];
    const float* attrs  = (const float*)d_in[2];
    const int*   batch  = (const int*)d_in[3];
    const int*   ei     = (const int*)d_in[4];
    const float* wv     = (const float*)d_in[5];
    const float* mlp_w1 = (const float*)d_in[6];
    const float* mlp_b1 = (const float*)d_in[7];
    const float* mlp_w2 = (const float*)d_in[8];
    const float* mlp_b2 = (const float*)d_in[9];
    const float* lin1w  = (const float*)d_in[10];
    const float* lin2w  = (const float*)d_in[11];
    const float* lin2b  = (const float*)d_in[12];
    const float* linw   = (const float*)d_in[13];
    const float* linb   = (const float*)d_in[14];
    const float* ow1    = (const float*)d_in[15];
    const float* ob1    = (const float*)d_in[16];
    const float* ow2    = (const float*)d_in[17];
    const float* ob2    = (const float*)d_in[18];

    const int N = in_sizes[0] / 3;       // 100000
    const int E = in_sizes[4] / 2;       // 1600000
    const int G = out_size;              // 1000

    char* w = (char*)d_ws;
    size_t off = 0;
    auto alloc = [&](size_t bytes) -> char* {
        char* p = w + off;
        off = (off + bytes + 255) & ~(size_t)255;
        return p;
    };
    int*       cnt       = (int*)alloc((size_t)N * 4);
    int*       row_start = (int*)alloc((size_t)(N + 1) * 4);
    int*       cursor    = (int*)alloc((size_t)N * 4);
    int*       carry     = (int*)alloc(1024 * 4);
    int*       carry_ex  = (int*)alloc(1024 * 4);
    float4*    e_pack    = (float4*)alloc((size_t)E * 16);
    float*     h         = (float*)alloc((size_t)N * HID * 4);
    _Float16*  xfh       = (_Float16*)alloc((size_t)N * FIL * 2);
    float*     agg       = (float*)alloc((size_t)N * FIL * 4);
    _Float16*  tab       = (_Float16*)alloc((size_t)2 * TBL * FIL * 2); // 2 MB
    float*     sums      = (float*)alloc((size_t)G * 4);
    float*     cnts      = (float*)alloc((size_t)G * 4);
    (void)ws_size;

    const int B = 256;
    const int nblk = (N + 1023) / 1024;

    // CSR build (once per call; ws re-poisoned each call)
    hipMemsetAsync(cnt, 0, (size_t)N * 4, stream);
    k_count<<<(E + B - 1) / B, B, 0, stream>>>(ei, E, cnt);
    k_scan_blk<<<nblk, 1024, 0, stream>>>(cnt, N, row_start, carry);
    k_scan_carry<<<1, 1024, 0, stream>>>(carry, nblk, carry_ex);
    k_scan_add<<<(N + B - 1) / B, B, 0, stream>>>(row_start, carry_ex, N, E, cursor);
    k_fill<<<(E + B - 1) / B, B, 0, stream>>>(pos, shifts, ei, E, cursor, e_pack);

    // W(d) tables (fp16) + fused embed/lin1
    k_table<<<(2 * TBL * 16 + B - 1) / B, B, 0, stream>>>(mlp_w1, mlp_b1, mlp_w2, mlp_b2, tab);
    k_embed_lin1<<<((size_t)N * 64 + B - 1) / B, B, 0, stream>>>(attrs, wv, lin1w, N, h, xfh);

    hipMemsetAsync(sums, 0, (size_t)G * 4, stream);
    hipMemsetAsync(cnts, 0, (size_t)G * 4, stream);

    const size_t gw = ((size_t)N * 64 + B - 1) / B;
    // layer 0
    k_edge_agg<<<gw, B, 0, stream>>>(e_pack, row_start, N, tab, xfh, agg);
    k_node_l0<<<gw, B, 0, stream>>>(agg, lin2w, lin2b, linw, linb,
                                    lin1w + 4096, N, h, xfh);
    // layer 1 (+ fused readout)
    k_edge_agg<<<gw, B, 0, stream>>>(e_pack, row_start, N, tab + (size_t)TBL * FIL, xfh, agg);
    k_node_l1<<<gw, B, 0, stream>>>(agg, lin2w + 4096, lin2b + 64, linw + 4096, linb + 64,
                                    h, batch, ow1, ob1, ow2, ob2, N, sums, cnts);

    k_finalize<<<(G + B - 1) / B, B, 0, stream>>>(sums, cnts, G, (float*)d_out);
}

// Round 7
// 1685.076 us; speedup vs baseline: 1.0416x; 1.0416x over previous
//
#include <hip/hip_runtime.h>
#include <math.h>

#define NBASES 16
#define HID 64
#define FIL 64
#define TBL 8192
#define DMAX 8.0f
#define TSCALE (8191.0f / 8.0f)

// ShiftedSoftplus: softplus(x) - log(2), overflow-safe form.
__device__ __forceinline__ float sspf(float x) {
    return fmaxf(x, 0.f) + __logf(1.f + __expf(-fabsf(x))) - 0.69314718056f;
}

// ---------------- CSR build: histogram of dst ----------------
__global__ void k_count(const int* __restrict__ ei, int E, int* __restrict__ cnt) {
    int e = blockIdx.x * blockDim.x + threadIdx.x;
    if (e >= E) return;
    atomicAdd(&cnt[ei[E + e]], 1);
}

// ---- 3-phase scan: per-block exclusive scan + carry, carry scan, add ----
__global__ void k_scan_blk(const int* __restrict__ cnt, int N,
                           int* __restrict__ row_start, int* __restrict__ carry) {
    __shared__ int s[1024];
    int tid = threadIdx.x;
    int idx = blockIdx.x * 1024 + tid;
    int v = (idx < N) ? cnt[idx] : 0;
    s[tid] = v;
    __syncthreads();
    for (int off = 1; off < 1024; off <<= 1) {
        int t = (tid >= off) ? s[tid - off] : 0;
        __syncthreads();
        s[tid] += t;
        __syncthreads();
    }
    if (idx < N) row_start[idx] = s[tid] - v;     // within-block exclusive
    if (tid == 1023) carry[blockIdx.x] = s[1023]; // block total
}

__global__ void k_scan_carry(const int* __restrict__ carry, int nblk,
                             int* __restrict__ carry_ex) {
    __shared__ int s[1024];
    int tid = threadIdx.x;
    int v = (tid < nblk) ? carry[tid] : 0;
    s[tid] = v;
    __syncthreads();
    for (int off = 1; off < 1024; off <<= 1) {
        int t = (tid >= off) ? s[tid - off] : 0;
        __syncthreads();
        s[tid] += t;
        __syncthreads();
    }
    if (tid < nblk) carry_ex[tid] = s[tid] - v;
}

__global__ void k_scan_add(int* __restrict__ row_start, const int* __restrict__ carry_ex,
                           int N, int E, int* __restrict__ cursor) {
    int i = blockIdx.x * blockDim.x + threadIdx.x;
    if (i >= N) return;
    int r = row_start[i] + carry_ex[i >> 10];
    row_start[i] = r;
    cursor[i] = r;
    if (i == 0) row_start[N] = E;
}

// fill sorted-edge records: {src, dst, d, C} packed in one float4
__global__ void k_fill(const float* __restrict__ pos, const float* __restrict__ shifts,
                       const int* __restrict__ ei, int E, int* __restrict__ cursor,
                       float4* __restrict__ e_pack) {
    int e = blockIdx.x * blockDim.x + threadIdx.x;
    if (e >= E) return;
    int s = ei[e], t = ei[E + e];
    float dx = pos[t * 3 + 0] - pos[s * 3 + 0] + shifts[e * 3 + 0];
    float dy = pos[t * 3 + 1] - pos[s * 3 + 1] + shifts[e * 3 + 1];
    float dz = pos[t * 3 + 2] - pos[s * 3 + 2] + shifts[e * 3 + 2];
    float d = sqrtf(dx * dx + dy * dy + dz * dz);
    float C = 0.5f * (cosf(d * 0.6283185307179586f) + 1.0f); // pi/CUTOFF = pi/5
    int p = atomicAdd(&cursor[t], 1);
    float4 rec;
    rec.x = __int_as_float(s);
    rec.y = __int_as_float(t);
    rec.z = d;
    rec.w = C;
    e_pack[p] = rec;
}

// ---------------- W(d) lookup tables (fp16): thread = (entry, 4-filter chunk) ----------------
__global__ void __launch_bounds__(256) k_table(
    const float* __restrict__ w1, const float* __restrict__ b1,
    const float* __restrict__ w2, const float* __restrict__ b2,
    _Float16* __restrict__ tab) {
    int i = blockIdx.x * blockDim.x + threadIdx.x; // ((l*TBL + ti)<<4) | chunk
    if (i >= 2 * TBL * 16) return;
    int chunk = i & 15;
    int ent = i >> 4;
    int l = ent >> 13;
    int ti = ent & (TBL - 1);
    int f0 = chunk * 4;
    const float* w1l = w1 + l * (FIL * NBASES);
    const float* b1l = b1 + l * FIL;
    const float* w2l = w2 + l * (FIL * FIL);
    const float* b2l = b2 + l * FIL;
    float d = (float)ti * (DMAX / (float)(TBL - 1));
    float g[16];
#pragma unroll
    for (int b = 0; b < NBASES; b++) {
        float u = d - (float)b * (5.0f / 15.0f);
        g[b] = __expf(-4.5f * u * u);
    }
    float a0 = b2l[f0 + 0], a1 = b2l[f0 + 1], a2 = b2l[f0 + 2], a3 = b2l[f0 + 3];
#pragma unroll 4
    for (int j = 0; j < FIL; j++) {
        float tt = b1l[j];
#pragma unroll
        for (int b = 0; b < NBASES; b++) tt += w1l[j * NBASES + b] * g[b];
        float hj = sspf(tt);
        a0 += w2l[(f0 + 0) * FIL + j] * hj;
        a1 += w2l[(f0 + 1) * FIL + j] * hj;
        a2 += w2l[(f0 + 2) * FIL + j] * hj;
        a3 += w2l[(f0 + 3) * FIL + j] * hj;
    }
    _Float16* o = tab + (size_t)ent * FIL + f0;
    o[0] = (_Float16)a0; o[1] = (_Float16)a1; o[2] = (_Float16)a2; o[3] = (_Float16)a3;
}

// helper: LDS-broadcast matvec, lane = output index. v staged in buf (64 floats, wave-private).
__device__ __forceinline__ float matvec64(const float* __restrict__ wrow, const float* __restrict__ buf) {
    const float4* w4 = (const float4*)wrow;
    const float4* b4 = (const float4*)buf;
    float acc = 0.f;
#pragma unroll
    for (int jc = 0; jc < 16; jc++) {
        float4 ww = w4[jc];   // per-lane row, L1-resident (16KB working set)
        float4 vv = b4[jc];   // uniform LDS address -> broadcast, conflict-free
        acc += ww.x * vv.x + ww.y * vv.y + ww.z * vv.z + ww.w * vv.w;
    }
    return acc;
}

// ---------------- fused embed + layer0 lin1 (wave per node, lane = feature) ----------------
__global__ void __launch_bounds__(256) k_embed_lin1(
    const float* __restrict__ attrs, const float* __restrict__ wv,
    const float* __restrict__ w, int N,
    float* __restrict__ h, _Float16* __restrict__ xfh) {
    __shared__ float buf[4][64];
    int n = (blockIdx.x * blockDim.x + threadIdx.x) >> 6;
    int lane = threadIdx.x & 63;
    int ws = threadIdx.x >> 6;
    if (n >= N) return;
    float a0 = attrs[n * 5 + 0], a1 = attrs[n * 5 + 1], a2 = attrs[n * 5 + 2],
          a3 = attrs[n * 5 + 3], a4 = attrs[n * 5 + 4];       // uniform -> broadcast
    const float* wr = wv + lane * 5;
    float hv = a0 * wr[0] + a1 * wr[1] + a2 * wr[2] + a3 * wr[3] + a4 * wr[4];
    h[(size_t)n * HID + lane] = hv;
    buf[ws][lane] = hv;                                        // wave-lockstep staging
    float xv = matvec64(w + lane * 64, buf[ws]);
    xfh[(size_t)n * FIL + lane] = (_Float16)xv;
}

// ---------------- edge aggregate: wave per node, fp16 gathers, 2x unrolled ----------------
__global__ void __launch_bounds__(256, 8) k_edge_agg(
    const float4* __restrict__ e_pack, const int* __restrict__ row_start, int N,
    const _Float16* __restrict__ tab, const _Float16* __restrict__ xf,
    float* __restrict__ agg) {
    int n = (blockIdx.x * blockDim.x + threadIdx.x) >> 6;
    int lane = threadIdx.x & 63;
    if (n >= N) return;
    int rs = row_start[n], re = row_start[n + 1];
    float acc = 0.f;
    int r = rs;
#define EDGE_TERM(ep) do { \
        int s_ = __float_as_int((ep).x); \
        float x_ = (ep).z * TSCALE; \
        int i0_ = (int)x_; if (i0_ > TBL - 2) i0_ = TBL - 2; \
        float fr_ = fminf(x_ - (float)i0_, 1.0f); \
        float t0_ = (float)tab[(size_t)i0_ * FIL + lane]; \
        float t1_ = (float)tab[(size_t)(i0_ + 1) * FIL + lane]; \
        float xv_ = (float)xf[(size_t)s_ * FIL + lane]; \
        acc += xv_ * (t0_ + (t1_ - t0_) * fr_) * (ep).w; \
    } while (0)
    for (; r + 2 <= re; r += 2) {
        float4 e0 = e_pack[r];
        float4 e1 = e_pack[r + 1];
        EDGE_TERM(e0);
        EDGE_TERM(e1);
    }
    if (r < re) {
        float4 e0 = e_pack[r];
        EDGE_TERM(e0);
    }
    agg[(size_t)n * FIL + lane] = acc;
#undef EDGE_TERM
}

// ---------------- fused layer-0 node update: h += lin(ssp(lin2(agg))); xf_next = h@lin1_1^T ----------------
__global__ void __launch_bounds__(256) k_node_l0(
    const float* __restrict__ agg,
    const float* __restrict__ lin2w, const float* __restrict__ lin2b,
    const float* __restrict__ linw, const float* __restrict__ linb,
    const float* __restrict__ lin1w_next, int N,
    float* __restrict__ h, _Float16* __restrict__ xfh) {
    __shared__ float buf[4][64];
    int n = (blockIdx.x * blockDim.x + threadIdx.x) >> 6;
    int lane = threadIdx.x & 63;
    int ws = threadIdx.x >> 6;
    if (n >= N) return;
    buf[ws][lane] = agg[(size_t)n * FIL + lane];
    float tmpv = sspf(lin2b[lane] + matvec64(lin2w + lane * 64, buf[ws]));
    buf[ws][lane] = tmpv;                                      // wave-lockstep: prior reads done
    float hnew = h[(size_t)n * HID + lane] + linb[lane] + matvec64(linw + lane * 64, buf[ws]);
    h[(size_t)n * HID + lane] = hnew;
    buf[ws][lane] = hnew;
    float xv = matvec64(lin1w_next + lane * 64, buf[ws]);
    xfh[(size_t)n * FIL + lane] = (_Float16)xv;
}

// ---------------- fused layer-1 node update + readout MLP -> per-node scalar o[n] (NO atomics) ----------------
__global__ void __launch_bounds__(256) k_node_ro(
    const float* __restrict__ agg,
    const float* __restrict__ lin2w, const float* __restrict__ lin2b,
    const float* __restrict__ linw, const float* __restrict__ linb,
    const float* __restrict__ h,
    const float* __restrict__ ow1, const float* __restrict__ ob1,
    const float* __restrict__ ow2, const float* __restrict__ ob2, int N,
    float* __restrict__ o) {
    __shared__ float buf[4][64];
    int n = (blockIdx.x * blockDim.x + threadIdx.x) >> 6;
    int lane = threadIdx.x & 63;
    int ws = threadIdx.x >> 6;
    if (n >= N) return;
    buf[ws][lane] = agg[(size_t)n * FIL + lane];
    float tmpv = sspf(lin2b[lane] + matvec64(lin2w + lane * 64, buf[ws]));
    buf[ws][lane] = tmpv;
    float hnew = h[(size_t)n * HID + lane] + linb[lane] + matvec64(linw + lane * 64, buf[ws]);
    buf[ws][lane] = hnew;                                      // h never written: consumed here
    float r = 0.f;
    if (lane < 32) {
        float racc = ob1[lane] + matvec64(ow1 + lane * 64, buf[ws]);
        r = sspf(racc) * ow2[lane];
    }
#pragma unroll
    for (int m = 1; m < 64; m <<= 1) r += __shfl_xor(r, m, 64);
    if (lane == 0) o[n] = r + ob2[0];
}

// ---------------- graph segment boundaries: b_start[g] = lower_bound(batch, g) ----------------
__global__ void k_bstart(const int* __restrict__ batch, int N, int G,
                         int* __restrict__ b_start) {
    int g = blockIdx.x * blockDim.x + threadIdx.x;
    if (g > G) return;
    int lo = 0, hi = N;
    while (lo < hi) {
        int mid = (lo + hi) >> 1;
        if (batch[mid] < g) lo = mid + 1;
        else hi = mid;
    }
    b_start[g] = lo;
}

// ---------------- per-graph mean over sorted o[] segment: wave per graph, no atomics ----------------
__global__ void k_gmean(const float* __restrict__ o, const int* __restrict__ b_start,
                        int G, float* __restrict__ out) {
    int g = (blockIdx.x * blockDim.x + threadIdx.x) >> 6;
    int lane = threadIdx.x & 63;
    if (g >= G) return;
    int rs = b_start[g], re = b_start[g + 1];
    float a = 0.f;
    for (int r = rs + lane; r < re; r += 64) a += o[r];
#pragma unroll
    for (int m = 1; m < 64; m <<= 1) a += __shfl_xor(a, m, 64);
    if (lane == 0) {
        float cnt = (float)(re - rs);
        out[g] = a / fmaxf(cnt, 1.0f);
    }
}

extern "C" void kernel_launch(void* const* d_in, const int* in_sizes, int n_in,
                              void* d_out, int out_size, void* d_ws, size_t ws_size,
                              hipStream_t stream) {
    const float* pos    = (const float*)d_in[0];
    const float* shifts = (const float*)d_in[1];
    const float* attrs  = (const float*)d_in[2];
    const int*   batch  = (const int*)d_in[3];
    const int*   ei     = (const int*)d_in[4];
    const float* wv     = (const float*)d_in[5];
    const float* mlp_w1 = (const float*)d_in[6];
    const float* mlp_b1 = (const float*)d_in[7];
    const float* mlp_w2 = (const float*)d_in[8];
    const float* mlp_b2 = (const float*)d_in[9];
    const float* lin1w  = (const float*)d_in[10];
    const float* lin2w  = (const float*)d_in[11];
    const float* lin2b  = (const float*)d_in[12];
    const float* linw   = (const float*)d_in[13];
    const float* linb   = (const float*)d_in[14];
    const float* ow1    = (const float*)d_in[15];
    const float* ob1    = (const float*)d_in[16];
    const float* ow2    = (const float*)d_in[17];
    const float* ob2    = (const float*)d_in[18];

    const int N = in_sizes[0] / 3;       // 100000
    const int E = in_sizes[4] / 2;       // 1600000
    const int G = out_size;              // 1000

    char* w = (char*)d_ws;
    size_t off = 0;
    auto alloc = [&](size_t bytes) -> char* {
        char* p = w + off;
        off = (off + bytes + 255) & ~(size_t)255;
        return p;
    };
    int*       cnt       = (int*)alloc((size_t)N * 4);
    int*       row_start = (int*)alloc((size_t)(N + 1) * 4);
    int*       cursor    = (int*)alloc((size_t)N * 4);
    int*       carry     = (int*)alloc(1024 * 4);
    int*       carry_ex  = (int*)alloc(1024 * 4);
    float4*    e_pack    = (float4*)alloc((size_t)E * 16);
    float*     h         = (float*)alloc((size_t)N * HID * 4);
    _Float16*  xfh       = (_Float16*)alloc((size_t)N * FIL * 2);
    float*     agg       = (float*)alloc((size_t)N * FIL * 4);
    _Float16*  tab       = (_Float16*)alloc((size_t)2 * TBL * FIL * 2); // 2 MB
    float*     o_node    = (float*)alloc((size_t)N * 4);
    int*       b_start   = (int*)alloc((size_t)(G + 1) * 4);
    (void)ws_size;

    const int B = 256;
    const int nblk = (N + 1023) / 1024;

    // CSR build (once per call; ws re-poisoned each call)
    hipMemsetAsync(cnt, 0, (size_t)N * 4, stream);
    k_count<<<(E + B - 1) / B, B, 0, stream>>>(ei, E, cnt);
    k_scan_blk<<<nblk, 1024, 0, stream>>>(cnt, N, row_start, carry);
    k_scan_carry<<<1, 1024, 0, stream>>>(carry, nblk, carry_ex);
    k_scan_add<<<(N + B - 1) / B, B, 0, stream>>>(row_start, carry_ex, N, E, cursor);
    k_fill<<<(E + B - 1) / B, B, 0, stream>>>(pos, shifts, ei, E, cursor, e_pack);

    // W(d) tables (fp16) + fused embed/lin1 + graph boundaries
    k_table<<<(2 * TBL * 16 + B - 1) / B, B, 0, stream>>>(mlp_w1, mlp_b1, mlp_w2, mlp_b2, tab);
    k_embed_lin1<<<((size_t)N * 64 + B - 1) / B, B, 0, stream>>>(attrs, wv, lin1w, N, h, xfh);
    k_bstart<<<(G + 1 + B - 1) / B, B, 0, stream>>>(batch, N, G, b_start);

    const size_t gw = ((size_t)N * 64 + B - 1) / B;
    // layer 0
    k_edge_agg<<<gw, B, 0, stream>>>(e_pack, row_start, N, tab, xfh, agg);
    k_node_l0<<<gw, B, 0, stream>>>(agg, lin2w, lin2b, linw, linb,
                                    lin1w + 4096, N, h, xfh);
    // layer 1 (+ fused readout -> per-node scalar, no atomics)
    k_edge_agg<<<gw, B, 0, stream>>>(e_pack, row_start, N, tab + (size_t)TBL * FIL, xfh, agg);
    k_node_ro<<<gw, B, 0, stream>>>(agg, lin2w + 4096, lin2b + 64, linw + 4096, linb + 64,
                                    h, ow1, ob1, ow2, ob2, N, o_node);
    // per-graph mean via sorted-batch segments
    k_gmean<<<((size_t)G * 64 + B - 1) / B, B, 0, stream>>>(o_node, b_start, G, (float*)d_out);
}

// Round 8
// 1306.331 us; speedup vs baseline: 1.3436x; 1.2899x over previous
//
#include <hip/hip_runtime.h>
#include <math.h>

#define NBASES 16
#define HID 64
#define FIL 64
#define TBL 8192
#define DMAX 8.0f
#define TSCALE (8191.0f / 8.0f)
#define NW 16          // waves (= nodes) per node-kernel block
#define BT (NW * 64)   // 1024 threads

// ShiftedSoftplus: softplus(x) - log(2), overflow-safe form.
__device__ __forceinline__ float sspf(float x) {
    return fmaxf(x, 0.f) + __logf(1.f + __expf(-fabsf(x))) - 0.69314718056f;
}

// ---------------- CSR build: histogram of dst ----------------
__global__ void k_count(const int* __restrict__ ei, int E, int* __restrict__ cnt) {
    int e = blockIdx.x * blockDim.x + threadIdx.x;
    if (e >= E) return;
    atomicAdd(&cnt[ei[E + e]], 1);
}

// ---- 3-phase scan: per-block exclusive scan + carry, carry scan, add ----
__global__ void k_scan_blk(const int* __restrict__ cnt, int N,
                           int* __restrict__ row_start, int* __restrict__ carry) {
    __shared__ int s[1024];
    int tid = threadIdx.x;
    int idx = blockIdx.x * 1024 + tid;
    int v = (idx < N) ? cnt[idx] : 0;
    s[tid] = v;
    __syncthreads();
    for (int off = 1; off < 1024; off <<= 1) {
        int t = (tid >= off) ? s[tid - off] : 0;
        __syncthreads();
        s[tid] += t;
        __syncthreads();
    }
    if (idx < N) row_start[idx] = s[tid] - v;     // within-block exclusive
    if (tid == 1023) carry[blockIdx.x] = s[1023]; // block total
}

__global__ void k_scan_carry(const int* __restrict__ carry, int nblk,
                             int* __restrict__ carry_ex) {
    __shared__ int s[1024];
    int tid = threadIdx.x;
    int v = (tid < nblk) ? carry[tid] : 0;
    s[tid] = v;
    __syncthreads();
    for (int off = 1; off < 1024; off <<= 1) {
        int t = (tid >= off) ? s[tid - off] : 0;
        __syncthreads();
        s[tid] += t;
        __syncthreads();
    }
    if (tid < nblk) carry_ex[tid] = s[tid] - v;
}

__global__ void k_scan_add(int* __restrict__ row_start, const int* __restrict__ carry_ex,
                           int N, int E, int* __restrict__ cursor) {
    int i = blockIdx.x * blockDim.x + threadIdx.x;
    if (i >= N) return;
    int r = row_start[i] + carry_ex[i >> 10];
    row_start[i] = r;
    cursor[i] = r;
    if (i == 0) row_start[N] = E;
}

// fill sorted-edge records: {src, dst, d, C} packed in one float4
__global__ void k_fill(const float* __restrict__ pos, const float* __restrict__ shifts,
                       const int* __restrict__ ei, int E, int* __restrict__ cursor,
                       float4* __restrict__ e_pack) {
    int e = blockIdx.x * blockDim.x + threadIdx.x;
    if (e >= E) return;
    int s = ei[e], t = ei[E + e];
    float dx = pos[t * 3 + 0] - pos[s * 3 + 0] + shifts[e * 3 + 0];
    float dy = pos[t * 3 + 1] - pos[s * 3 + 1] + shifts[e * 3 + 1];
    float dz = pos[t * 3 + 2] - pos[s * 3 + 2] + shifts[e * 3 + 2];
    float d = sqrtf(dx * dx + dy * dy + dz * dz);
    float C = 0.5f * (cosf(d * 0.6283185307179586f) + 1.0f); // pi/CUTOFF = pi/5
    int p = atomicAdd(&cursor[t], 1);
    float4 rec;
    rec.x = __int_as_float(s);
    rec.y = __int_as_float(t);
    rec.z = d;
    rec.w = C;
    e_pack[p] = rec;
}

// ---------------- W(d) lookup tables (fp16): thread = (entry, 4-filter chunk) ----------------
__global__ void __launch_bounds__(256) k_table(
    const float* __restrict__ w1, const float* __restrict__ b1,
    const float* __restrict__ w2, const float* __restrict__ b2,
    _Float16* __restrict__ tab) {
    int i = blockIdx.x * blockDim.x + threadIdx.x; // ((l*TBL + ti)<<4) | chunk
    if (i >= 2 * TBL * 16) return;
    int chunk = i & 15;
    int ent = i >> 4;
    int l = ent >> 13;
    int ti = ent & (TBL - 1);
    int f0 = chunk * 4;
    const float* w1l = w1 + l * (FIL * NBASES);
    const float* b1l = b1 + l * FIL;
    const float* w2l = w2 + l * (FIL * FIL);
    const float* b2l = b2 + l * FIL;
    float d = (float)ti * (DMAX / (float)(TBL - 1));
    float g[16];
#pragma unroll
    for (int b = 0; b < NBASES; b++) {
        float u = d - (float)b * (5.0f / 15.0f);
        g[b] = __expf(-4.5f * u * u);
    }
    float a0 = b2l[f0 + 0], a1 = b2l[f0 + 1], a2 = b2l[f0 + 2], a3 = b2l[f0 + 3];
#pragma unroll 4
    for (int j = 0; j < FIL; j++) {
        float tt = b1l[j];
#pragma unroll
        for (int b = 0; b < NBASES; b++) tt += w1l[j * NBASES + b] * g[b];
        float hj = sspf(tt);
        a0 += w2l[(f0 + 0) * FIL + j] * hj;
        a1 += w2l[(f0 + 1) * FIL + j] * hj;
        a2 += w2l[(f0 + 2) * FIL + j] * hj;
        a3 += w2l[(f0 + 3) * FIL + j] * hj;
    }
    _Float16* o = tab + (size_t)ent * FIL + f0;
    o[0] = (_Float16)a0; o[1] = (_Float16)a1; o[2] = (_Float16)a2; o[3] = (_Float16)a3;
}

// ---- XOR-swizzled LDS weight staging: lw[f*64 + (j^f)] = w[f*64 + j] ----
// Staging writes and per-lane reads both hit 2 lanes/bank (free, m136).
__device__ __forceinline__ void stage_xor(const float* __restrict__ w, float* lw,
                                          int nelem, int tid, int nthr) {
    for (int idx = tid; idx < nelem; idx += nthr) {
        int f = idx >> 6, j = idx & 63;
        lw[(f << 6) + (j ^ f)] = w[idx];
    }
}

// matvec: out[lane] = sum_j lw_row(lane)[j] * buf[j]; weights in XOR-swizzled LDS,
// v broadcast via uniform float4 LDS reads. Conflict-free (j^lane spans 0..63 -> 2/bank).
__device__ __forceinline__ float matvec_xor(const float* __restrict__ lw, int lane,
                                            const float* __restrict__ buf) {
    float acc = 0.f;
    const float4* b4 = (const float4*)buf;
    const int base = lane << 6;
#pragma unroll
    for (int jc = 0; jc < 16; jc++) {
        float4 vv = b4[jc];
        acc += lw[base + ((jc * 4 + 0) ^ lane)] * vv.x;
        acc += lw[base + ((jc * 4 + 1) ^ lane)] * vv.y;
        acc += lw[base + ((jc * 4 + 2) ^ lane)] * vv.z;
        acc += lw[base + ((jc * 4 + 3) ^ lane)] * vv.w;
    }
    return acc;
}

// ---------------- fused embed + layer0 lin1 (wave per node; lin1 weights in LDS) ----------------
__global__ void __launch_bounds__(BT) k_embed_lin1(
    const float* __restrict__ attrs, const float* __restrict__ wv,
    const float* __restrict__ w, int N,
    float* __restrict__ h, _Float16* __restrict__ xfh) {
    __shared__ float lw[4096];
    __shared__ float buf[NW][64];
    int tid = threadIdx.x;
    stage_xor(w, lw, 4096, tid, BT);
    __syncthreads();
    int lane = tid & 63, ws = tid >> 6;
    int n = blockIdx.x * NW + ws;
    if (n >= N) return;
    float a0 = attrs[n * 5 + 0], a1 = attrs[n * 5 + 1], a2 = attrs[n * 5 + 2],
          a3 = attrs[n * 5 + 3], a4 = attrs[n * 5 + 4];
    const float* wr = wv + lane * 5;   // 1.3KB total, L1-resident
    float hv = a0 * wr[0] + a1 * wr[1] + a2 * wr[2] + a3 * wr[3] + a4 * wr[4];
    h[(size_t)n * HID + lane] = hv;
    buf[ws][lane] = hv;                // same-wave LDS ops are in-order: safe
    float xv = matvec_xor(lw, lane, buf[ws]);
    xfh[(size_t)n * FIL + lane] = (_Float16)xv;
}

// ---------------- edge aggregate: wave per node, fp16 gathers, 2x unrolled ----------------
__global__ void __launch_bounds__(256, 8) k_edge_agg(
    const float4* __restrict__ e_pack, const int* __restrict__ row_start, int N,
    const _Float16* __restrict__ tab, const _Float16* __restrict__ xf,
    float* __restrict__ agg) {
    int n = (blockIdx.x * blockDim.x + threadIdx.x) >> 6;
    int lane = threadIdx.x & 63;
    if (n >= N) return;
    int rs = row_start[n], re = row_start[n + 1];
    float acc = 0.f;
    int r = rs;
#define EDGE_TERM(ep) do { \
        int s_ = __float_as_int((ep).x); \
        float x_ = (ep).z * TSCALE; \
        int i0_ = (int)x_; if (i0_ > TBL - 2) i0_ = TBL - 2; \
        float fr_ = fminf(x_ - (float)i0_, 1.0f); \
        float t0_ = (float)tab[(size_t)i0_ * FIL + lane]; \
        float t1_ = (float)tab[(size_t)(i0_ + 1) * FIL + lane]; \
        float xv_ = (float)xf[(size_t)s_ * FIL + lane]; \
        acc += xv_ * (t0_ + (t1_ - t0_) * fr_) * (ep).w; \
    } while (0)
    for (; r + 2 <= re; r += 2) {
        float4 e0 = e_pack[r];
        float4 e1 = e_pack[r + 1];
        EDGE_TERM(e0);
        EDGE_TERM(e1);
    }
    if (r < re) {
        float4 e0 = e_pack[r];
        EDGE_TERM(e0);
    }
    agg[(size_t)n * FIL + lane] = acc;
#undef EDGE_TERM
}

// ---------------- fused layer-0 node update (weights in LDS): h += lin(ssp(lin2(agg))); xf_next ----------------
__global__ void __launch_bounds__(BT) k_node_l0(
    const float* __restrict__ agg,
    const float* __restrict__ lin2w, const float* __restrict__ lin2b,
    const float* __restrict__ linw, const float* __restrict__ linb,
    const float* __restrict__ lin1w_next, int N,
    float* __restrict__ h, _Float16* __restrict__ xfh) {
    __shared__ float lw2[4096], lwl[4096], lw1[4096];  // 48KB
    __shared__ float buf[NW][64];
    int tid = threadIdx.x;
    stage_xor(lin2w, lw2, 4096, tid, BT);
    stage_xor(linw, lwl, 4096, tid, BT);
    stage_xor(lin1w_next, lw1, 4096, tid, BT);
    __syncthreads();
    int lane = tid & 63, ws = tid >> 6;
    int n = blockIdx.x * NW + ws;
    if (n >= N) return;
    buf[ws][lane] = agg[(size_t)n * FIL + lane];
    float tmpv = sspf(lin2b[lane] + matvec_xor(lw2, lane, buf[ws]));
    buf[ws][lane] = tmpv;              // in-order LDS within wave: prior reads complete
    float hnew = h[(size_t)n * HID + lane] + linb[lane] + matvec_xor(lwl, lane, buf[ws]);
    h[(size_t)n * HID + lane] = hnew;
    buf[ws][lane] = hnew;
    float xv = matvec_xor(lw1, lane, buf[ws]);
    xfh[(size_t)n * FIL + lane] = (_Float16)xv;
}

// ---------------- fused layer-1 node update + readout MLP -> per-node scalar (no atomics) ----------------
__global__ void __launch_bounds__(BT) k_node_ro(
    const float* __restrict__ agg,
    const float* __restrict__ lin2w, const float* __restrict__ lin2b,
    const float* __restrict__ linw, const float* __restrict__ linb,
    const float* __restrict__ h,
    const float* __restrict__ ow1, const float* __restrict__ ob1,
    const float* __restrict__ ow2, const float* __restrict__ ob2, int N,
    float* __restrict__ o) {
    __shared__ float lw2[4096], lwl[4096], lo1[2048];  // 40KB
    __shared__ float buf[NW][64];
    int tid = threadIdx.x;
    stage_xor(lin2w, lw2, 4096, tid, BT);
    stage_xor(linw, lwl, 4096, tid, BT);
    stage_xor(ow1, lo1, 2048, tid, BT);
    __syncthreads();
    int lane = tid & 63, ws = tid >> 6;
    int n = blockIdx.x * NW + ws;
    if (n >= N) return;
    buf[ws][lane] = agg[(size_t)n * FIL + lane];
    float tmpv = sspf(lin2b[lane] + matvec_xor(lw2, lane, buf[ws]));
    buf[ws][lane] = tmpv;
    float hnew = h[(size_t)n * HID + lane] + linb[lane] + matvec_xor(lwl, lane, buf[ws]);
    buf[ws][lane] = hnew;              // h never written: consumed here
    float r = 0.f;
    if (lane < 32) {
        float racc = ob1[lane] + matvec_xor(lo1, lane, buf[ws]);
        r = sspf(racc) * ow2[lane];
    }
#pragma unroll
    for (int m = 1; m < 64; m <<= 1) r += __shfl_xor(r, m, 64);
    if (lane == 0) o[n] = r + ob2[0];
}

// ---------------- graph segment boundaries: b_start[g] = lower_bound(batch, g) ----------------
__global__ void k_bstart(const int* __restrict__ batch, int N, int G,
                         int* __restrict__ b_start) {
    int g = blockIdx.x * blockDim.x + threadIdx.x;
    if (g > G) return;
    int lo = 0, hi = N;
    while (lo < hi) {
        int mid = (lo + hi) >> 1;
        if (batch[mid] < g) lo = mid + 1;
        else hi = mid;
    }
    b_start[g] = lo;
}

// ---------------- per-graph mean over sorted o[] segment: wave per graph, no atomics ----------------
__global__ void k_gmean(const float* __restrict__ o, const int* __restrict__ b_start,
                        int G, float* __restrict__ out) {
    int g = (blockIdx.x * blockDim.x + threadIdx.x) >> 6;
    int lane = threadIdx.x & 63;
    if (g >= G) return;
    int rs = b_start[g], re = b_start[g + 1];
    float a = 0.f;
    for (int r = rs + lane; r < re; r += 64) a += o[r];
#pragma unroll
    for (int m = 1; m < 64; m <<= 1) a += __shfl_xor(a, m, 64);
    if (lane == 0) {
        float cnt = (float)(re - rs);
        out[g] = a / fmaxf(cnt, 1.0f);
    }
}

extern "C" void kernel_launch(void* const* d_in, const int* in_sizes, int n_in,
                              void* d_out, int out_size, void* d_ws, size_t ws_size,
                              hipStream_t stream) {
    const float* pos    = (const float*)d_in[0];
    const float* shifts = (const float*)d_in[1];
    const float* attrs  = (const float*)d_in[2];
    const int*   batch  = (const int*)d_in[3];
    const int*   ei     = (const int*)d_in[4];
    const float* wv     = (const float*)d_in[5];
    const float* mlp_w1 = (const float*)d_in[6];
    const float* mlp_b1 = (const float*)d_in[7];
    const float* mlp_w2 = (const float*)d_in[8];
    const float* mlp_b2 = (const float*)d_in[9];
    const float* lin1w  = (const float*)d_in[10];
    const float* lin2w  = (const float*)d_in[11];
    const float* lin2b  = (const float*)d_in[12];
    const float* linw   = (const float*)d_in[13];
    const float* linb   = (const float*)d_in[14];
    const float* ow1    = (const float*)d_in[15];
    const float* ob1    = (const float*)d_in[16];
    const float* ow2    = (const float*)d_in[17];
    const float* ob2    = (const float*)d_in[18];

    const int N = in_sizes[0] / 3;       // 100000
    const int E = in_sizes[4] / 2;       // 1600000
    const int G = out_size;              // 1000

    char* w = (char*)d_ws;
    size_t off = 0;
    auto alloc = [&](size_t bytes) -> char* {
        char* p = w + off;
        off = (off + bytes + 255) & ~(size_t)255;
        return p;
    };
    int*       cnt       = (int*)alloc((size_t)N * 4);
    int*       row_start = (int*)alloc((size_t)(N + 1) * 4);
    int*       cursor    = (int*)alloc((size_t)N * 4);
    int*       carry     = (int*)alloc(1024 * 4);
    int*       carry_ex  = (int*)alloc(1024 * 4);
    float4*    e_pack    = (float4*)alloc((size_t)E * 16);
    float*     h         = (float*)alloc((size_t)N * HID * 4);
    _Float16*  xfh       = (_Float16*)alloc((size_t)N * FIL * 2);
    float*     agg       = (float*)alloc((size_t)N * FIL * 4);
    _Float16*  tab       = (_Float16*)alloc((size_t)2 * TBL * FIL * 2); // 2 MB
    float*     o_node    = (float*)alloc((size_t)N * 4);
    int*       b_start   = (int*)alloc((size_t)(G + 1) * 4);
    (void)ws_size;

    const int B = 256;
    const int nblk = (N + 1023) / 1024;
    const int nodeblk = (N + NW - 1) / NW;

    // CSR build (once per call; ws re-poisoned each call)
    hipMemsetAsync(cnt, 0, (size_t)N * 4, stream);
    k_count<<<(E + B - 1) / B, B, 0, stream>>>(ei, E, cnt);
    k_scan_blk<<<nblk, 1024, 0, stream>>>(cnt, N, row_start, carry);
    k_scan_carry<<<1, 1024, 0, stream>>>(carry, nblk, carry_ex);
    k_scan_add<<<(N + B - 1) / B, B, 0, stream>>>(row_start, carry_ex, N, E, cursor);
    k_fill<<<(E + B - 1) / B, B, 0, stream>>>(pos, shifts, ei, E, cursor, e_pack);

    // W(d) tables (fp16) + fused embed/lin1 + graph boundaries
    k_table<<<(2 * TBL * 16 + B - 1) / B, B, 0, stream>>>(mlp_w1, mlp_b1, mlp_w2, mlp_b2, tab);
    k_embed_lin1<<<nodeblk, BT, 0, stream>>>(attrs, wv, lin1w, N, h, xfh);
    k_bstart<<<(G + 1 + B - 1) / B, B, 0, stream>>>(batch, N, G, b_start);

    const size_t gw = ((size_t)N * 64 + B - 1) / B;
    // layer 0
    k_edge_agg<<<gw, B, 0, stream>>>(e_pack, row_start, N, tab, xfh, agg);
    k_node_l0<<<nodeblk, BT, 0, stream>>>(agg, lin2w, lin2b, linw, linb,
                                          lin1w + 4096, N, h, xfh);
    // layer 1 (+ fused readout -> per-node scalar, no atomics)
    k_edge_agg<<<gw, B, 0, stream>>>(e_pack, row_start, N, tab + (size_t)TBL * FIL, xfh, agg);
    k_node_ro<<<nodeblk, BT, 0, stream>>>(agg, lin2w + 4096, lin2b + 64, linw + 4096, linb + 64,
                                          h, ow1, ob1, ow2, ob2, N, o_node);
    // per-graph mean via sorted-batch segments
    k_gmean<<<((size_t)G * 64 + B - 1) / B, B, 0, stream>>>(o_node, b_start, G, (float*)d_out);
}

// Round 9
// 1094.666 us; speedup vs baseline: 1.6034x; 1.1934x over previous
//
#include <hip/hip_runtime.h>
#include <math.h>

#define NBASES 16
#define HID 64
#define FIL 64
#define TBL 8192
#define DMAX 8.0f
#define TSCALE (8191.0f / 8.0f)

// ShiftedSoftplus: softplus(x) - log(2), overflow-safe form.
__device__ __forceinline__ float sspf(float x) {
    return fmaxf(x, 0.f) + __logf(1.f + __expf(-fabsf(x))) - 0.69314718056f;
}

// ---------------- CSR build: histogram of dst ----------------
__global__ void k_count(const int* __restrict__ ei, int E, int* __restrict__ cnt) {
    int e = blockIdx.x * blockDim.x + threadIdx.x;
    if (e >= E) return;
    atomicAdd(&cnt[ei[E + e]], 1);
}

// ---- 3-phase scan ----
__global__ void k_scan_blk(const int* __restrict__ cnt, int N,
                           int* __restrict__ row_start, int* __restrict__ carry) {
    __shared__ int s[1024];
    int tid = threadIdx.x;
    int idx = blockIdx.x * 1024 + tid;
    int v = (idx < N) ? cnt[idx] : 0;
    s[tid] = v;
    __syncthreads();
    for (int off = 1; off < 1024; off <<= 1) {
        int t = (tid >= off) ? s[tid - off] : 0;
        __syncthreads();
        s[tid] += t;
        __syncthreads();
    }
    if (idx < N) row_start[idx] = s[tid] - v;
    if (tid == 1023) carry[blockIdx.x] = s[1023];
}

__global__ void k_scan_carry(const int* __restrict__ carry, int nblk,
                             int* __restrict__ carry_ex) {
    __shared__ int s[1024];
    int tid = threadIdx.x;
    int v = (tid < nblk) ? carry[tid] : 0;
    s[tid] = v;
    __syncthreads();
    for (int off = 1; off < 1024; off <<= 1) {
        int t = (tid >= off) ? s[tid - off] : 0;
        __syncthreads();
        s[tid] += t;
        __syncthreads();
    }
    if (tid < nblk) carry_ex[tid] = s[tid] - v;
}

__global__ void k_scan_add(int* __restrict__ row_start, const int* __restrict__ carry_ex,
                           int N, int E, int* __restrict__ cursor) {
    int i = blockIdx.x * blockDim.x + threadIdx.x;
    if (i >= N) return;
    int r = row_start[i] + carry_ex[i >> 10];
    row_start[i] = r;
    cursor[i] = r;
    if (i == 0) row_start[N] = E;
}

// fill sorted-edge records: {src, dst, d, C}
__global__ void k_fill(const float* __restrict__ pos, const float* __restrict__ shifts,
                       const int* __restrict__ ei, int E, int* __restrict__ cursor,
                       float4* __restrict__ e_pack) {
    int e = blockIdx.x * blockDim.x + threadIdx.x;
    if (e >= E) return;
    int s = ei[e], t = ei[E + e];
    float dx = pos[t * 3 + 0] - pos[s * 3 + 0] + shifts[e * 3 + 0];
    float dy = pos[t * 3 + 1] - pos[s * 3 + 1] + shifts[e * 3 + 1];
    float dz = pos[t * 3 + 2] - pos[s * 3 + 2] + shifts[e * 3 + 2];
    float d = sqrtf(dx * dx + dy * dy + dz * dz);
    float C = 0.5f * (cosf(d * 0.6283185307179586f) + 1.0f); // pi/CUTOFF = pi/5
    int p = atomicAdd(&cursor[t], 1);
    float4 rec;
    rec.x = __int_as_float(s);
    rec.y = __int_as_float(t);
    rec.z = d;
    rec.w = C;
    e_pack[p] = rec;
}

// ---------------- W(d) lookup tables (fp16): thread = (entry, 4-filter chunk) ----------------
__global__ void __launch_bounds__(256) k_table(
    const float* __restrict__ w1, const float* __restrict__ b1,
    const float* __restrict__ w2, const float* __restrict__ b2,
    _Float16* __restrict__ tab) {
    int i = blockIdx.x * blockDim.x + threadIdx.x;
    if (i >= 2 * TBL * 16) return;
    int chunk = i & 15;
    int ent = i >> 4;
    int l = ent >> 13;
    int ti = ent & (TBL - 1);
    int f0 = chunk * 4;
    const float* w1l = w1 + l * (FIL * NBASES);
    const float* b1l = b1 + l * FIL;
    const float* w2l = w2 + l * (FIL * FIL);
    const float* b2l = b2 + l * FIL;
    float d = (float)ti * (DMAX / (float)(TBL - 1));
    float g[16];
#pragma unroll
    for (int b = 0; b < NBASES; b++) {
        float u = d - (float)b * (5.0f / 15.0f);
        g[b] = __expf(-4.5f * u * u);
    }
    float a0 = b2l[f0 + 0], a1 = b2l[f0 + 1], a2 = b2l[f0 + 2], a3 = b2l[f0 + 3];
#pragma unroll 4
    for (int j = 0; j < FIL; j++) {
        float tt = b1l[j];
#pragma unroll
        for (int b = 0; b < NBASES; b++) tt += w1l[j * NBASES + b] * g[b];
        float hj = sspf(tt);
        a0 += w2l[(f0 + 0) * FIL + j] * hj;
        a1 += w2l[(f0 + 1) * FIL + j] * hj;
        a2 += w2l[(f0 + 2) * FIL + j] * hj;
        a3 += w2l[(f0 + 3) * FIL + j] * hj;
    }
    _Float16* o = tab + (size_t)ent * FIL + f0;
    o[0] = (_Float16)a0; o[1] = (_Float16)a1; o[2] = (_Float16)a2; o[3] = (_Float16)a3;
}

// pack adjacent table rows: tab2[ent][f] = (W_ti[f], W_{ti+1}[f]) as fp16x2 in a uint
__global__ void k_pack(const _Float16* __restrict__ tab, unsigned int* __restrict__ tab2) {
    int i = blockIdx.x * blockDim.x + threadIdx.x;
    if (i >= 2 * TBL * 64) return;
    int ent = i >> 6, f = i & 63;
    int l = ent >> 13, ti = ent & (TBL - 1);
    int tn = ti < TBL - 1 ? ti + 1 : ti;
    union { unsigned int u; _Float16 h[2]; } cv;
    cv.h[0] = tab[((size_t)ent << 6) + f];
    cv.h[1] = tab[((size_t)((l << 13) + tn) << 6) + f];
    tab2[((size_t)ent << 6) + f] = cv.u;
}

// ---------------- embed: h = attrs @ Wv^T (thread per node; wv uniform -> s_load) ----------------
__global__ void __launch_bounds__(256) k_embed(
    const float* __restrict__ attrs, const float* __restrict__ wv,
    int N, float* __restrict__ h) {
    int n = blockIdx.x * blockDim.x + threadIdx.x;
    if (n >= N) return;
    float a0 = attrs[n * 5 + 0], a1 = attrs[n * 5 + 1], a2 = attrs[n * 5 + 2],
          a3 = attrs[n * 5 + 3], a4 = attrs[n * 5 + 4];
    float4* out = (float4*)(h + (size_t)n * HID);
#pragma unroll
    for (int c = 0; c < 16; c++) {
        float4 o;
        float* op = (float*)&o;
#pragma unroll
        for (int q = 0; q < 4; q++) {
            const float* wr = wv + (c * 4 + q) * 5;
            op[q] = a0 * wr[0] + a1 * wr[1] + a2 * wr[2] + a3 * wr[3] + a4 * wr[4];
        }
        out[c] = o;
    }
}

// ======== chunked matvec kernels: thread = (node, 16-output chunk), c = blockIdx.y ========
// acc[16] static regs; input row streamed as float4 (L1-reuse); W via block-uniform s_load.
#define MV_BODY(VIN, W)                                                    \
    int n = blockIdx.x * blockDim.x + threadIdx.x;                         \
    int c = blockIdx.y;                                                    \
    if (n >= N) return;                                                    \
    const float* wbase = (W) + (c << 4) * 64;                              \
    float acc[16];                                                         \
    const float4* vr = (const float4*)((VIN) + (size_t)n * 64);            \
    _Pragma("unroll")                                                      \
    for (int jq = 0; jq < 16; jq++) {                                      \
        float4 v = vr[jq];                                                 \
        _Pragma("unroll")                                                  \
        for (int k = 0; k < 16; k++) {                                     \
            const float* w = wbase + k * 64 + jq * 4;                      \
            if (jq == 0) acc[k] = 0.f;                                     \
            acc[k] += v.x * w[0] + v.y * w[1] + v.z * w[2] + v.w * w[3];   \
        }                                                                  \
    }

// lin1: xf_f16 = vin @ W^T (no bias)
__global__ void __launch_bounds__(256, 4) k_mv_f16(
    const float* __restrict__ vin, const float* __restrict__ W, int N,
    _Float16* __restrict__ vout) {
    MV_BODY(vin, W)
    union { unsigned int u[8]; _Float16 h[16]; } pk;
#pragma unroll
    for (int k = 0; k < 16; k++) pk.h[k] = (_Float16)acc[k];
    unsigned int* o = (unsigned int*)(vout + (size_t)n * 64 + (c << 4));
#pragma unroll
    for (int p = 0; p < 8; p++) o[p] = pk.u[p];
}

// nu_a: tmp = ssp(vin @ W^T + b)
__global__ void __launch_bounds__(256, 4) k_mv_ssp(
    const float* __restrict__ vin, const float* __restrict__ W,
    const float* __restrict__ bias, int N, float* __restrict__ vout) {
    MV_BODY(vin, W)
    float* o = vout + (size_t)n * 64 + (c << 4);
#pragma unroll
    for (int k = 0; k < 16; k++) o[k] = sspf(acc[k] + bias[(c << 4) + k]);
}

// nu_b: h += vin @ W^T + b
__global__ void __launch_bounds__(256, 4) k_mv_addh(
    const float* __restrict__ vin, const float* __restrict__ W,
    const float* __restrict__ bias, int N, float* __restrict__ h) {
    MV_BODY(vin, W)
    float* o = h + (size_t)n * 64 + (c << 4);
#pragma unroll
    for (int k = 0; k < 16; k++) o[k] += acc[k] + bias[(c << 4) + k];
}

// readout: thread = (node, 8-hidden chunk); partial scalar -> o_part[c*N+n] (no atomics)
__global__ void __launch_bounds__(256, 4) k_ro_chunk(
    const float* __restrict__ h, const float* __restrict__ ow1,
    const float* __restrict__ ob1, const float* __restrict__ ow2, int N,
    float* __restrict__ o_part) {
    int n = blockIdx.x * blockDim.x + threadIdx.x;
    int c = blockIdx.y;             // 0..3 -> hidden units c*8..c*8+7
    if (n >= N) return;
    const float* wbase = ow1 + (c << 3) * 64;
    float acc[8];
    const float4* vr = (const float4*)(h + (size_t)n * 64);
#pragma unroll
    for (int jq = 0; jq < 16; jq++) {
        float4 v = vr[jq];
#pragma unroll
        for (int k = 0; k < 8; k++) {
            const float* w = wbase + k * 64 + jq * 4;
            if (jq == 0) acc[k] = 0.f;
            acc[k] += v.x * w[0] + v.y * w[1] + v.z * w[2] + v.w * w[3];
        }
    }
    float part = 0.f;
#pragma unroll
    for (int k = 0; k < 8; k++) {
        int kk = (c << 3) + k;
        part += sspf(acc[k] + ob1[kk]) * ow2[kk];
    }
    o_part[(size_t)c * N + n] = part;
}

// ---------------- edge aggregate: wave per node, packed-pair table, 4x unroll ----------------
__global__ void __launch_bounds__(256, 8) k_edge_agg(
    const float4* __restrict__ e_pack, const int* __restrict__ row_start, int N,
    const unsigned int* __restrict__ tab2, const _Float16* __restrict__ xf,
    float* __restrict__ agg) {
    int n = (blockIdx.x * blockDim.x + threadIdx.x) >> 6;
    int lane = threadIdx.x & 63;
    if (n >= N) return;
    int rs = row_start[n], re = row_start[n + 1];
    float acc = 0.f;
    int r = rs;
#define EDGE_TERM(ep) do { \
        int s_ = __float_as_int((ep).x); \
        float x_ = (ep).z * TSCALE; \
        int i0_ = (int)x_; if (i0_ > TBL - 2) i0_ = TBL - 2; \
        float fr_ = fminf(x_ - (float)i0_, 1.0f); \
        union { unsigned int u; _Float16 hh[2]; } cv_; \
        cv_.u = tab2[((size_t)i0_ << 6) + lane]; \
        float t0_ = (float)cv_.hh[0], t1_ = (float)cv_.hh[1]; \
        float xv_ = (float)xf[((size_t)s_ << 6) + lane]; \
        acc += xv_ * (t0_ + (t1_ - t0_) * fr_) * (ep).w; \
    } while (0)
    for (; r + 4 <= re; r += 4) {
        float4 e0 = e_pack[r], e1 = e_pack[r + 1], e2 = e_pack[r + 2], e3 = e_pack[r + 3];
        EDGE_TERM(e0); EDGE_TERM(e1); EDGE_TERM(e2); EDGE_TERM(e3);
    }
    for (; r < re; r++) {
        float4 e0 = e_pack[r];
        EDGE_TERM(e0);
    }
    agg[(size_t)n * 64 + lane] = acc;
#undef EDGE_TERM
}

// ---------------- graph segment boundaries ----------------
__global__ void k_bstart(const int* __restrict__ batch, int N, int G,
                         int* __restrict__ b_start) {
    int g = blockIdx.x * blockDim.x + threadIdx.x;
    if (g > G) return;
    int lo = 0, hi = N;
    while (lo < hi) {
        int mid = (lo + hi) >> 1;
        if (batch[mid] < g) lo = mid + 1;
        else hi = mid;
    }
    b_start[g] = lo;
}

// ---------------- per-graph mean over sorted o_part segments ----------------
__global__ void k_gmean(const float* __restrict__ o_part, const int* __restrict__ b_start,
                        int N, int G, const float* __restrict__ ob2,
                        float* __restrict__ out) {
    int g = (blockIdx.x * blockDim.x + threadIdx.x) >> 6;
    int lane = threadIdx.x & 63;
    if (g >= G) return;
    int rs = b_start[g], re = b_start[g + 1];
    float a = 0.f;
    for (int r = rs + lane; r < re; r += 64)
        a += o_part[r] + o_part[(size_t)N + r] + o_part[(size_t)2 * N + r] + o_part[(size_t)3 * N + r];
#pragma unroll
    for (int m = 1; m < 64; m <<= 1) a += __shfl_xor(a, m, 64);
    if (lane == 0) {
        float cnt = (float)(re - rs);
        out[g] = a / fmaxf(cnt, 1.0f) + ob2[0];
    }
}

extern "C" void kernel_launch(void* const* d_in, const int* in_sizes, int n_in,
                              void* d_out, int out_size, void* d_ws, size_t ws_size,
                              hipStream_t stream) {
    const float* pos    = (const float*)d_in[0];
    const float* shifts = (const float*)d_in[1];
    const float* attrs  = (const float*)d_in[2];
    const int*   batch  = (const int*)d_in[3];
    const int*   ei     = (const int*)d_in[4];
    const float* wv     = (const float*)d_in[5];
    const float* mlp_w1 = (const float*)d_in[6];
    const float* mlp_b1 = (const float*)d_in[7];
    const float* mlp_w2 = (const float*)d_in[8];
    const float* mlp_b2 = (const float*)d_in[9];
    const float* lin1w  = (const float*)d_in[10];
    const float* lin2w  = (const float*)d_in[11];
    const float* lin2b  = (const float*)d_in[12];
    const float* linw   = (const float*)d_in[13];
    const float* linb   = (const float*)d_in[14];
    const float* ow1    = (const float*)d_in[15];
    const float* ob1    = (const float*)d_in[16];
    const float* ow2    = (const float*)d_in[17];
    const float* ob2    = (const float*)d_in[18];

    const int N = in_sizes[0] / 3;       // 100000
    const int E = in_sizes[4] / 2;       // 1600000
    const int G = out_size;              // 1000

    char* w = (char*)d_ws;
    size_t off = 0;
    auto alloc = [&](size_t bytes) -> char* {
        char* p = w + off;
        off = (off + bytes + 255) & ~(size_t)255;
        return p;
    };
    int*          cnt       = (int*)alloc((size_t)N * 4);
    int*          row_start = (int*)alloc((size_t)(N + 1) * 4);
    int*          cursor    = (int*)alloc((size_t)N * 4);
    int*          carry     = (int*)alloc(1024 * 4);
    int*          carry_ex  = (int*)alloc(1024 * 4);
    float4*       e_pack    = (float4*)alloc((size_t)E * 16);
    float*        h         = (float*)alloc((size_t)N * HID * 4);
    _Float16*     xfh       = (_Float16*)alloc((size_t)N * FIL * 2);
    float*        agg       = (float*)alloc((size_t)N * FIL * 4);
    float*        tmp       = (float*)alloc((size_t)N * HID * 4);
    _Float16*     tab       = (_Float16*)alloc((size_t)2 * TBL * FIL * 2);
    unsigned int* tab2      = (unsigned int*)alloc((size_t)2 * TBL * FIL * 4);
    float*        o_part    = (float*)alloc((size_t)4 * N * 4);
    int*          b_start   = (int*)alloc((size_t)(G + 1) * 4);
    (void)ws_size;

    const int B = 256;
    const int nblk = (N + 1023) / 1024;
    const dim3 mvgrid((N + B - 1) / B, 4);

    // CSR build
    hipMemsetAsync(cnt, 0, (size_t)N * 4, stream);
    k_count<<<(E + B - 1) / B, B, 0, stream>>>(ei, E, cnt);
    k_scan_blk<<<nblk, 1024, 0, stream>>>(cnt, N, row_start, carry);
    k_scan_carry<<<1, 1024, 0, stream>>>(carry, nblk, carry_ex);
    k_scan_add<<<(N + B - 1) / B, B, 0, stream>>>(row_start, carry_ex, N, E, cursor);
    k_fill<<<(E + B - 1) / B, B, 0, stream>>>(pos, shifts, ei, E, cursor, e_pack);

    // tables + packing + embed + boundaries
    k_table<<<(2 * TBL * 16 + B - 1) / B, B, 0, stream>>>(mlp_w1, mlp_b1, mlp_w2, mlp_b2, tab);
    k_pack<<<(2 * TBL * 64 + B - 1) / B, B, 0, stream>>>(tab, tab2);
    k_embed<<<(N + B - 1) / B, B, 0, stream>>>(attrs, wv, N, h);
    k_bstart<<<(G + 1 + B - 1) / B, B, 0, stream>>>(batch, N, G, b_start);

    const size_t gw = ((size_t)N * 64 + B - 1) / B;
    // layer 0
    k_mv_f16<<<mvgrid, B, 0, stream>>>(h, lin1w, N, xfh);
    k_edge_agg<<<gw, B, 0, stream>>>(e_pack, row_start, N, tab2, xfh, agg);
    k_mv_ssp<<<mvgrid, B, 0, stream>>>(agg, lin2w, lin2b, N, tmp);
    k_mv_addh<<<mvgrid, B, 0, stream>>>(tmp, linw, linb, N, h);
    // layer 1
    k_mv_f16<<<mvgrid, B, 0, stream>>>(h, lin1w + 4096, N, xfh);
    k_edge_agg<<<gw, B, 0, stream>>>(e_pack, row_start, N, tab2 + (size_t)TBL * FIL, xfh, agg);
    k_mv_ssp<<<mvgrid, B, 0, stream>>>(agg, lin2w + 4096, lin2b + 64, N, tmp);
    k_mv_addh<<<mvgrid, B, 0, stream>>>(tmp, linw + 4096, linb + 64, N, h);
    // readout (4 partials per node, no atomics) + per-graph mean
    k_ro_chunk<<<mvgrid, B, 0, stream>>>(h, ow1, ob1, ow2, N, o_part);
    k_gmean<<<((size_t)G * 64 + B - 1) / B, B, 0, stream>>>(o_part, b_start, N, G, ob2, (float*)d_out);
}

// Round 10
// 773.981 us; speedup vs baseline: 2.2677x; 1.4143x over previous
//
#include <hip/hip_runtime.h>
#include <math.h>

#define NBASES 16
#define HID 64
#define FIL 64
#define TBL 8192
#define DMAX 8.0f
#define TSCALE (8191.0f / 8.0f)

// ShiftedSoftplus: softplus(x) - log(2), overflow-safe form.
__device__ __forceinline__ float sspf(float x) {
    return fmaxf(x, 0.f) + __logf(1.f + __expf(-fabsf(x))) - 0.69314718056f;
}

// ---------------- CSR build: histogram of dst ----------------
__global__ void k_count(const int* __restrict__ ei, int E, int* __restrict__ cnt) {
    int e = blockIdx.x * blockDim.x + threadIdx.x;
    if (e >= E) return;
    atomicAdd(&cnt[ei[E + e]], 1);
}

// ---- 3-phase scan ----
__global__ void k_scan_blk(const int* __restrict__ cnt, int N,
                           int* __restrict__ row_start, int* __restrict__ carry) {
    __shared__ int s[1024];
    int tid = threadIdx.x;
    int idx = blockIdx.x * 1024 + tid;
    int v = (idx < N) ? cnt[idx] : 0;
    s[tid] = v;
    __syncthreads();
    for (int off = 1; off < 1024; off <<= 1) {
        int t = (tid >= off) ? s[tid - off] : 0;
        __syncthreads();
        s[tid] += t;
        __syncthreads();
    }
    if (idx < N) row_start[idx] = s[tid] - v;
    if (tid == 1023) carry[blockIdx.x] = s[1023];
}

__global__ void k_scan_carry(const int* __restrict__ carry, int nblk,
                             int* __restrict__ carry_ex) {
    __shared__ int s[1024];
    int tid = threadIdx.x;
    int v = (tid < nblk) ? carry[tid] : 0;
    s[tid] = v;
    __syncthreads();
    for (int off = 1; off < 1024; off <<= 1) {
        int t = (tid >= off) ? s[tid - off] : 0;
        __syncthreads();
        s[tid] += t;
        __syncthreads();
    }
    if (tid < nblk) carry_ex[tid] = s[tid] - v;
}

__global__ void k_scan_add(int* __restrict__ row_start, const int* __restrict__ carry_ex,
                           int N, int E, int* __restrict__ cursor) {
    int i = blockIdx.x * blockDim.x + threadIdx.x;
    if (i >= N) return;
    int r = row_start[i] + carry_ex[i >> 10];
    row_start[i] = r;
    cursor[i] = r;
    if (i == 0) row_start[N] = E;
}

// fill sorted-edge records: {src, dst, d, C}
__global__ void k_fill(const float* __restrict__ pos, const float* __restrict__ shifts,
                       const int* __restrict__ ei, int E, int* __restrict__ cursor,
                       float4* __restrict__ e_pack) {
    int e = blockIdx.x * blockDim.x + threadIdx.x;
    if (e >= E) return;
    int s = ei[e], t = ei[E + e];
    float dx = pos[t * 3 + 0] - pos[s * 3 + 0] + shifts[e * 3 + 0];
    float dy = pos[t * 3 + 1] - pos[s * 3 + 1] + shifts[e * 3 + 1];
    float dz = pos[t * 3 + 2] - pos[s * 3 + 2] + shifts[e * 3 + 2];
    float d = sqrtf(dx * dx + dy * dy + dz * dz);
    float C = 0.5f * (cosf(d * 0.6283185307179586f) + 1.0f); // pi/CUTOFF = pi/5
    int p = atomicAdd(&cursor[t], 1);
    float4 rec;
    rec.x = __int_as_float(s);
    rec.y = __int_as_float(t);
    rec.z = d;
    rec.w = C;
    e_pack[p] = rec;
}

// ---------------- W(d) lookup tables (fp16): thread = (entry, 4-filter chunk) ----------------
__global__ void __launch_bounds__(256) k_table(
    const float* __restrict__ w1, const float* __restrict__ b1,
    const float* __restrict__ w2, const float* __restrict__ b2,
    _Float16* __restrict__ tab) {
    int i = blockIdx.x * blockDim.x + threadIdx.x;
    if (i >= 2 * TBL * 16) return;
    int chunk = i & 15;
    int ent = i >> 4;
    int l = ent >> 13;
    int ti = ent & (TBL - 1);
    int f0 = chunk * 4;
    const float* w1l = w1 + l * (FIL * NBASES);
    const float* b1l = b1 + l * FIL;
    const float* w2l = w2 + l * (FIL * FIL);
    const float* b2l = b2 + l * FIL;
    float d = (float)ti * (DMAX / (float)(TBL - 1));
    float g[16];
#pragma unroll
    for (int b = 0; b < NBASES; b++) {
        float u = d - (float)b * (5.0f / 15.0f);
        g[b] = __expf(-4.5f * u * u);
    }
    float a0 = b2l[f0 + 0], a1 = b2l[f0 + 1], a2 = b2l[f0 + 2], a3 = b2l[f0 + 3];
#pragma unroll 4
    for (int j = 0; j < FIL; j++) {
        float tt = b1l[j];
#pragma unroll
        for (int b = 0; b < NBASES; b++) tt += w1l[j * NBASES + b] * g[b];
        float hj = sspf(tt);
        a0 += w2l[(f0 + 0) * FIL + j] * hj;
        a1 += w2l[(f0 + 1) * FIL + j] * hj;
        a2 += w2l[(f0 + 2) * FIL + j] * hj;
        a3 += w2l[(f0 + 3) * FIL + j] * hj;
    }
    _Float16* o = tab + (size_t)ent * FIL + f0;
    o[0] = (_Float16)a0; o[1] = (_Float16)a1; o[2] = (_Float16)a2; o[3] = (_Float16)a3;
}

// pack adjacent table rows: tab2[ent][f] = (W_ti[f], W_{ti+1}[f]) as fp16x2 in a uint
__global__ void k_pack(const _Float16* __restrict__ tab, unsigned int* __restrict__ tab2) {
    int i = blockIdx.x * blockDim.x + threadIdx.x;
    if (i >= 2 * TBL * 64) return;
    int ent = i >> 6, f = i & 63;
    int l = ent >> 13, ti = ent & (TBL - 1);
    int tn = ti < TBL - 1 ? ti + 1 : ti;
    union { unsigned int u; _Float16 h[2]; } cv;
    cv.h[0] = tab[((size_t)ent << 6) + f];
    cv.h[1] = tab[((size_t)((l << 13) + tn) << 6) + f];
    tab2[((size_t)ent << 6) + f] = cv.u;
}

// ---------------- fused embed + layer0 lin1 (thread per node, single pass) ----------------
__global__ void __launch_bounds__(256, 2) k_embed_lin1(
    const float* __restrict__ attrs, const float* __restrict__ wv,
    const float* __restrict__ W, int N,
    float* __restrict__ h, _Float16* __restrict__ xfh) {
    int n = blockIdx.x * blockDim.x + threadIdx.x;
    if (n >= N) return;
    float a0 = attrs[n * 5 + 0], a1 = attrs[n * 5 + 1], a2 = attrs[n * 5 + 2],
          a3 = attrs[n * 5 + 3], a4 = attrs[n * 5 + 4];
    float hv[64];
#pragma unroll
    for (int f = 0; f < 64; f++) {
        const float* wr = wv + f * 5;   // uniform -> s_load
        hv[f] = a0 * wr[0] + a1 * wr[1] + a2 * wr[2] + a3 * wr[3] + a4 * wr[4];
    }
    float4* hw = (float4*)(h + (size_t)n * HID);
#pragma unroll
    for (int c = 0; c < 16; c++) {
        float4 o; o.x = hv[c*4]; o.y = hv[c*4+1]; o.z = hv[c*4+2]; o.w = hv[c*4+3];
        hw[c] = o;
    }
    for (int c = 0; c < 16; c++) {      // runtime c: acc4 static, hv[j] static
        float b0 = 0.f, b1 = 0.f, b2 = 0.f, b3 = 0.f;
#pragma unroll
        for (int j = 0; j < 64; j++) {
            float t = hv[j];
            b0 += W[(c * 4 + 0) * 64 + j] * t;
            b1 += W[(c * 4 + 1) * 64 + j] * t;
            b2 += W[(c * 4 + 2) * 64 + j] * t;
            b3 += W[(c * 4 + 3) * 64 + j] * t;
        }
        union { unsigned int u[2]; _Float16 hh[4]; } pk;
        pk.hh[0] = (_Float16)b0; pk.hh[1] = (_Float16)b1;
        pk.hh[2] = (_Float16)b2; pk.hh[3] = (_Float16)b3;
        *(uint2*)(xfh + (size_t)n * FIL + c * 4) = make_uint2(pk.u[0], pk.u[1]);
    }
}

// ---------------- lin1 (layer 1): xfh = h @ W^T, single input pass ----------------
__global__ void __launch_bounds__(256, 2) k_lin1(
    const float* __restrict__ h, const float* __restrict__ W, int N,
    _Float16* __restrict__ xfh) {
    int n = blockIdx.x * blockDim.x + threadIdx.x;
    if (n >= N) return;
    float hv[64];
    const float4* hr = (const float4*)(h + (size_t)n * HID);
#pragma unroll
    for (int c = 0; c < 16; c++) {
        float4 v = hr[c];
        hv[c*4] = v.x; hv[c*4+1] = v.y; hv[c*4+2] = v.z; hv[c*4+3] = v.w;
    }
    for (int c = 0; c < 16; c++) {
        float b0 = 0.f, b1 = 0.f, b2 = 0.f, b3 = 0.f;
#pragma unroll
        for (int j = 0; j < 64; j++) {
            float t = hv[j];
            b0 += W[(c * 4 + 0) * 64 + j] * t;
            b1 += W[(c * 4 + 1) * 64 + j] * t;
            b2 += W[(c * 4 + 2) * 64 + j] * t;
            b3 += W[(c * 4 + 3) * 64 + j] * t;
        }
        union { unsigned int u[2]; _Float16 hh[4]; } pk;
        pk.hh[0] = (_Float16)b0; pk.hh[1] = (_Float16)b1;
        pk.hh[2] = (_Float16)b2; pk.hh[3] = (_Float16)b3;
        *(uint2*)(xfh + (size_t)n * FIL + c * 4) = make_uint2(pk.u[0], pk.u[1]);
    }
}

// ---------------- fused node update: h += lin(ssp(lin2(agg))) — no tmp buffer ----------------
__global__ void __launch_bounds__(256, 2) k_nu(
    const float* __restrict__ agg,
    const float* __restrict__ lin2w, const float* __restrict__ lin2b,
    const float* __restrict__ linw, const float* __restrict__ linb,
    int N, float* __restrict__ h) {
    int n = blockIdx.x * blockDim.x + threadIdx.x;
    if (n >= N) return;
    float tv[64];
#pragma unroll
    for (int j = 0; j < 64; j++) tv[j] = lin2b[j];
    const float4* ar = (const float4*)(agg + (size_t)n * FIL);
    for (int jq = 0; jq < 16; jq++) {   // runtime jq: tv[j] static via inner unroll
        float4 v = ar[jq];
#pragma unroll
        for (int j = 0; j < 64; j++) {
            const float* w = lin2w + j * 64 + jq * 4;  // uniform -> s_load
            tv[j] += w[0] * v.x + w[1] * v.y + w[2] * v.z + w[3] * v.w;
        }
    }
#pragma unroll
    for (int j = 0; j < 64; j++) tv[j] = sspf(tv[j]);
    float4* hr = (float4*)(h + (size_t)n * HID);
    for (int c = 0; c < 16; c++) {      // runtime c: stream h chunks RMW
        float4 hh = hr[c];
        float b0 = linb[c*4+0], b1 = linb[c*4+1], b2 = linb[c*4+2], b3 = linb[c*4+3];
#pragma unroll
        for (int j = 0; j < 64; j++) {
            float t = tv[j];
            b0 += linw[(c * 4 + 0) * 64 + j] * t;
            b1 += linw[(c * 4 + 1) * 64 + j] * t;
            b2 += linw[(c * 4 + 2) * 64 + j] * t;
            b3 += linw[(c * 4 + 3) * 64 + j] * t;
        }
        hh.x += b0; hh.y += b1; hh.z += b2; hh.w += b3;
        hr[c] = hh;
    }
}

// ---------------- readout: single pass over h, one scalar per node ----------------
__global__ void __launch_bounds__(256, 2) k_ro(
    const float* __restrict__ h, const float* __restrict__ ow1,
    const float* __restrict__ ob1, const float* __restrict__ ow2,
    const float* __restrict__ ob2, int N, float* __restrict__ o_node) {
    int n = blockIdx.x * blockDim.x + threadIdx.x;
    if (n >= N) return;
    float acc[32];
#pragma unroll
    for (int k = 0; k < 32; k++) acc[k] = ob1[k];
    const float4* vr = (const float4*)(h + (size_t)n * HID);
    for (int jq = 0; jq < 16; jq++) {
        float4 v = vr[jq];
#pragma unroll
        for (int k = 0; k < 32; k++) {
            const float* w = ow1 + k * 64 + jq * 4;  // uniform -> s_load
            acc[k] += w[0] * v.x + w[1] * v.y + w[2] * v.z + w[3] * v.w;
        }
    }
    float o = ob2[0];
#pragma unroll
    for (int k = 0; k < 32; k++) o += sspf(acc[k]) * ow2[k];
    o_node[n] = o;
}

// ---------------- edge aggregate: wave per node, packed-pair table, 4x unroll ----------------
__global__ void __launch_bounds__(256, 8) k_edge_agg(
    const float4* __restrict__ e_pack, const int* __restrict__ row_start, int N,
    const unsigned int* __restrict__ tab2, const _Float16* __restrict__ xf,
    float* __restrict__ agg) {
    int n = (blockIdx.x * blockDim.x + threadIdx.x) >> 6;
    int lane = threadIdx.x & 63;
    if (n >= N) return;
    int rs = row_start[n], re = row_start[n + 1];
    float acc = 0.f;
    int r = rs;
#define EDGE_TERM(ep) do { \
        int s_ = __float_as_int((ep).x); \
        float x_ = (ep).z * TSCALE; \
        int i0_ = (int)x_; if (i0_ > TBL - 2) i0_ = TBL - 2; \
        float fr_ = fminf(x_ - (float)i0_, 1.0f); \
        union { unsigned int u; _Float16 hh[2]; } cv_; \
        cv_.u = tab2[((size_t)i0_ << 6) + lane]; \
        float t0_ = (float)cv_.hh[0], t1_ = (float)cv_.hh[1]; \
        float xv_ = (float)xf[((size_t)s_ << 6) + lane]; \
        acc += xv_ * (t0_ + (t1_ - t0_) * fr_) * (ep).w; \
    } while (0)
    for (; r + 4 <= re; r += 4) {
        float4 e0 = e_pack[r], e1 = e_pack[r + 1], e2 = e_pack[r + 2], e3 = e_pack[r + 3];
        EDGE_TERM(e0); EDGE_TERM(e1); EDGE_TERM(e2); EDGE_TERM(e3);
    }
    for (; r < re; r++) {
        float4 e0 = e_pack[r];
        EDGE_TERM(e0);
    }
    agg[(size_t)n * 64 + lane] = acc;
#undef EDGE_TERM
}

// ---------------- graph segment boundaries ----------------
__global__ void k_bstart(const int* __restrict__ batch, int N, int G,
                         int* __restrict__ b_start) {
    int g = blockIdx.x * blockDim.x + threadIdx.x;
    if (g > G) return;
    int lo = 0, hi = N;
    while (lo < hi) {
        int mid = (lo + hi) >> 1;
        if (batch[mid] < g) lo = mid + 1;
        else hi = mid;
    }
    b_start[g] = lo;
}

// ---------------- per-graph mean over sorted o_node segments ----------------
__global__ void k_gmean(const float* __restrict__ o_node, const int* __restrict__ b_start,
                        int G, float* __restrict__ out) {
    int g = (blockIdx.x * blockDim.x + threadIdx.x) >> 6;
    int lane = threadIdx.x & 63;
    if (g >= G) return;
    int rs = b_start[g], re = b_start[g + 1];
    float a = 0.f;
    for (int r = rs + lane; r < re; r += 64) a += o_node[r];
#pragma unroll
    for (int m = 1; m < 64; m <<= 1) a += __shfl_xor(a, m, 64);
    if (lane == 0) {
        float cnt = (float)(re - rs);
        out[g] = a / fmaxf(cnt, 1.0f);
    }
}

extern "C" void kernel_launch(void* const* d_in, const int* in_sizes, int n_in,
                              void* d_out, int out_size, void* d_ws, size_t ws_size,
                              hipStream_t stream) {
    const float* pos    = (const float*)d_in[0];
    const float* shifts = (const float*)d_in[1];
    const float* attrs  = (const float*)d_in[2];
    const int*   batch  = (const int*)d_in[3];
    const int*   ei     = (const int*)d_in[4];
    const float* wv     = (const float*)d_in[5];
    const float* mlp_w1 = (const float*)d_in[6];
    const float* mlp_b1 = (const float*)d_in[7];
    const float* mlp_w2 = (const float*)d_in[8];
    const float* mlp_b2 = (const float*)d_in[9];
    const float* lin1w  = (const float*)d_in[10];
    const float* lin2w  = (const float*)d_in[11];
    const float* lin2b  = (const float*)d_in[12];
    const float* linw   = (const float*)d_in[13];
    const float* linb   = (const float*)d_in[14];
    const float* ow1    = (const float*)d_in[15];
    const float* ob1    = (const float*)d_in[16];
    const float* ow2    = (const float*)d_in[17];
    const float* ob2    = (const float*)d_in[18];

    const int N = in_sizes[0] / 3;       // 100000
    const int E = in_sizes[4] / 2;       // 1600000
    const int G = out_size;              // 1000

    char* w = (char*)d_ws;
    size_t off = 0;
    auto alloc = [&](size_t bytes) -> char* {
        char* p = w + off;
        off = (off + bytes + 255) & ~(size_t)255;
        return p;
    };
    int*          cnt       = (int*)alloc((size_t)N * 4);
    int*          row_start = (int*)alloc((size_t)(N + 1) * 4);
    int*          cursor    = (int*)alloc((size_t)N * 4);
    int*          carry     = (int*)alloc(1024 * 4);
    int*          carry_ex  = (int*)alloc(1024 * 4);
    float4*       e_pack    = (float4*)alloc((size_t)E * 16);
    float*        h         = (float*)alloc((size_t)N * HID * 4);
    _Float16*     xfh       = (_Float16*)alloc((size_t)N * FIL * 2);
    float*        agg       = (float*)alloc((size_t)N * FIL * 4);
    _Float16*     tab       = (_Float16*)alloc((size_t)2 * TBL * FIL * 2);
    unsigned int* tab2      = (unsigned int*)alloc((size_t)2 * TBL * FIL * 4);
    float*        o_node    = (float*)alloc((size_t)N * 4);
    int*          b_start   = (int*)alloc((size_t)(G + 1) * 4);
    (void)ws_size;

    const int B = 256;
    const int nblk = (N + 1023) / 1024;
    const int ng = (N + B - 1) / B;

    // CSR build
    hipMemsetAsync(cnt, 0, (size_t)N * 4, stream);
    k_count<<<(E + B - 1) / B, B, 0, stream>>>(ei, E, cnt);
    k_scan_blk<<<nblk, 1024, 0, stream>>>(cnt, N, row_start, carry);
    k_scan_carry<<<1, 1024, 0, stream>>>(carry, nblk, carry_ex);
    k_scan_add<<<ng, B, 0, stream>>>(row_start, carry_ex, N, E, cursor);
    k_fill<<<(E + B - 1) / B, B, 0, stream>>>(pos, shifts, ei, E, cursor, e_pack);

    // tables + packing + embed/lin1 + boundaries
    k_table<<<(2 * TBL * 16 + B - 1) / B, B, 0, stream>>>(mlp_w1, mlp_b1, mlp_w2, mlp_b2, tab);
    k_pack<<<(2 * TBL * 64 + B - 1) / B, B, 0, stream>>>(tab, tab2);
    k_embed_lin1<<<ng, B, 0, stream>>>(attrs, wv, lin1w, N, h, xfh);
    k_bstart<<<(G + 1 + B - 1) / B, B, 0, stream>>>(batch, N, G, b_start);

    const size_t gw = ((size_t)N * 64 + B - 1) / B;
    // layer 0
    k_edge_agg<<<gw, B, 0, stream>>>(e_pack, row_start, N, tab2, xfh, agg);
    k_nu<<<ng, B, 0, stream>>>(agg, lin2w, lin2b, linw, linb, N, h);
    // layer 1
    k_lin1<<<ng, B, 0, stream>>>(h, lin1w + 4096, N, xfh);
    k_edge_agg<<<gw, B, 0, stream>>>(e_pack, row_start, N, tab2 + (size_t)TBL * FIL, xfh, agg);
    k_nu<<<ng, B, 0, stream>>>(agg, lin2w + 4096, lin2b + 64, linw + 4096, linb + 64, N, h);
    // readout + per-graph mean
    k_ro<<<ng, B, 0, stream>>>(h, ow1, ob1, ow2, ob2, N, o_node);
    k_gmean<<<((size_t)G * 64 + B - 1) / B, B, 0, stream>>>(o_node, b_start, G, (float*)d_out);
}